// Round 4
// baseline (345.828 us; speedup 1.0000x reference)
//
#include <hip/hip_runtime.h>

#define WW 320          // input width/height
#define OWID 314        // output cols
#define OHEI 314        // output rows
#define BB 64           // batch
#define SW 6            // output cols per thread (6 cols -> exactly 12 floats = 3 x float4)
#define NSTRIP 53       // ceil(314/6); last strip clamped+masked
#define RPB 20          // output rows per band
#define NBAND 16        // 16*20 = 320 >= 314; tail rows masked
#define NROWS (RPB + 6) // 26 input rows streamed per thread
#define NTH 256
#define NBLK ((BB * NBAND * NSTRIP) / NTH)   // 64*16*53/256 = 212 exactly (one round)

// 12 uniform float4 loads: 3 per plane covering 12 consecutive floats.
__device__ __forceinline__ void load_row(
    const float* __restrict__ X0, const float* __restrict__ X1,
    const float* __restrict__ Y0, const float* __restrict__ Y1,
    int off, float4 r[12])
{
    r[0]  = *(const float4*)(X0 + off);
    r[1]  = *(const float4*)(X0 + off + 4);
    r[2]  = *(const float4*)(X0 + off + 8);
    r[3]  = *(const float4*)(X1 + off);
    r[4]  = *(const float4*)(X1 + off + 4);
    r[5]  = *(const float4*)(X1 + off + 8);
    r[6]  = *(const float4*)(Y0 + off);
    r[7]  = *(const float4*)(Y0 + off + 4);
    r[8]  = *(const float4*)(Y0 + off + 8);
    r[9]  = *(const float4*)(Y1 + off);
    r[10] = *(const float4*)(Y1 + off + 4);
    r[11] = *(const float4*)(Y1 + off + 8);
}

// 6 horizontal 7-tap sums of the 5 channel-combined moments for one loaded row.
// h[q*6+j], moment q in {sx,sy,sxx,syy,sxy}, output col j.
__device__ __forceinline__ void math_row(const float4 r[12], float h[30])
{
    float x0[12] = {r[0].x,r[0].y,r[0].z,r[0].w, r[1].x,r[1].y,r[1].z,r[1].w, r[2].x,r[2].y,r[2].z,r[2].w};
    float x1[12] = {r[3].x,r[3].y,r[3].z,r[3].w, r[4].x,r[4].y,r[4].z,r[4].w, r[5].x,r[5].y,r[5].z,r[5].w};
    float y0[12] = {r[6].x,r[6].y,r[6].z,r[6].w, r[7].x,r[7].y,r[7].z,r[7].w, r[8].x,r[8].y,r[8].z,r[8].w};
    float y1[12] = {r[9].x,r[9].y,r[9].z,r[9].w, r[10].x,r[10].y,r[10].z,r[10].w, r[11].x,r[11].y,r[11].z,r[11].w};

    float sx[12], sy[12], sxx[12], syy[12], sxy[12];
    #pragma unroll
    for (int j = 0; j < 12; ++j) {
        sx[j]  = x0[j] + x1[j];
        sy[j]  = y0[j] + y1[j];
        sxx[j] = x0[j] * x0[j] + x1[j] * x1[j];
        syy[j] = y0[j] * y0[j] + y1[j] * y1[j];
        sxy[j] = x0[j] * y0[j] + x1[j] * y1[j];
    }
    #pragma unroll
    for (int q = 0; q < 5; ++q) {
        const float* m = (q == 0) ? sx : (q == 1) ? sy : (q == 2) ? sxx : (q == 3) ? syy : sxy;
        float t = ((m[0] + m[1]) + (m[2] + m[3])) + ((m[4] + m[5]) + m[6]);
        h[q * 6 + 0] = t;
        #pragma unroll
        for (int j = 1; j < 6; ++j) {
            t = t - m[j - 1] + m[j + 6];
            h[q * 6 + j] = t;
        }
    }
}

// 1 wave/SIMD by design (grid = 212 <= 256 CUs, single round; more blocks do
// NOT co-reside per rounds 0-1) — use the full 512-VGPR budget for the ring.
__global__ __launch_bounds__(NTH, 1) void ssim_main(
    const float* __restrict__ X, const float* __restrict__ Y,
    const float* __restrict__ dr, double* __restrict__ acc,
    unsigned* __restrict__ counter, float* __restrict__ out)
{
    const int wi   = blockIdx.x * NTH + threadIdx.x;   // grid sized exactly
    const int s    = wi % NSTRIP;
    const int g    = wi / NSTRIP;
    const int band = g % NBAND;
    const int b    = g / NBAND;
    const int r0   = band * RPB;
    int cb = s * SW;
    if (cb > WW - 12) cb = WW - 12;          // clamp last strip (s=52: 312->308)

    const size_t plane = (size_t)WW * WW;
    const float* X0 = X + (size_t)b * 2 * plane;
    const float* X1 = X0 + plane;
    const float* Y0 = Y + (size_t)b * 2 * plane;
    const float* Y1 = Y0 + plane;

    const float d  = dr[b];
    const float C1 = (0.01f * d) * (0.01f * d);
    const float C2 = (0.03f * d) * (0.03f * d);

    // Dedup mask: thread s owns output cols [s*SW, s*SW+SW); after clamping,
    // leading cols belong to the previous strip. cb+j <= 313 < OWID always.
    float cm[SW];
    #pragma unroll
    for (int j = 0; j < SW; ++j) cm[j] = (cb + j >= s * SW) ? 1.0f : 0.0f;

    // Ring of last 7 rows' h-sums; zero-init so first 7 expires are no-ops.
    float ring[7][30];
    #pragma unroll
    for (int k = 0; k < 7; ++k)
        #pragma unroll
        for (int q = 0; q < 30; ++q) ring[k][q] = 0.0f;

    float v[30];
    #pragma unroll
    for (int q = 0; q < 30; ++q) v[q] = 0.0f;

    // Depth-2 ping-pong row buffers; fully unrolled stream -> all indices
    // (i&1, i%7) static, no rotation movs.
    float4 buf[2][12];
    load_row(X0, X1, Y0, Y1, r0 * WW + cb, buf[0]);

    float ssum = 0.0f;
    const float inv = 1.0f / 49.0f;
    const float cn  = 49.0f / 48.0f;

    #pragma unroll
    for (int i = 0; i < NROWS; ++i) {
        if (i + 1 < NROWS) {                  // prefetch row r0+i+1 (static guard)
            const int rn = min(r0 + i + 1, WW - 1);   // clamp: tail band masked below
            load_row(X0, X1, Y0, Y1, rn * WW + cb, buf[(i + 1) & 1]);
        }

        float h[30];
        math_row(buf[i & 1], h);              // row r0+i; next row already in flight

        const int slot = i % 7;               // static under full unroll
        #pragma unroll
        for (int q = 0; q < 30; ++q) {
            v[q] += h[q] - ring[slot][q];     // add row i, expire row i-7
            ring[slot][q] = h[q];
        }

        if (i >= 6) {                         // static guard
            const int t = r0 + i - 6;         // output row
            if (t < OHEI) {                   // runtime tail-band mask
                #pragma unroll
                for (int j = 0; j < SW; ++j) {
                    float ux  = v[j]       * inv, uy  = v[6 + j]  * inv;
                    float uxx = v[12 + j]  * inv, uyy = v[18 + j] * inv, uxy = v[24 + j] * inv;
                    float vx  = cn * (uxx - ux * ux);
                    float vy  = cn * (uyy - uy * uy);
                    float vxy = cn * (uxy - ux * uy);
                    float A1  = 2.0f * ux * uy + C1;
                    float A2  = 2.0f * vxy + C2;
                    float B1  = ux * ux + uy * uy + C1;
                    float B2  = vx + vy + C2;
                    ssum += cm[j] * (A1 * A2) / (B1 * B2);
                }
            }
        }
    }

    // ---- reduction: wave shuffle (double) -> LDS -> one atomic per block ----
    double local = (double)ssum;
    #pragma unroll
    for (int off = 32; off > 0; off >>= 1)
        local += __shfl_down(local, off, 64);
    __shared__ double wsum[NTH / 64];
    const int lane = threadIdx.x & 63, wid = threadIdx.x >> 6;
    if (lane == 0) wsum[wid] = local;
    __syncthreads();
    if (threadIdx.x == 0) {
        double tot = (wsum[0] + wsum[1]) + (wsum[2] + wsum[3]);
        atomicAdd(acc, tot);
        __threadfence();
        unsigned ticket = atomicAdd(counter, 1u);
        if (ticket == NBLK - 1) {
            double stot = atomicAdd(acc, 0.0);   // device-scope coherent read
            const double N = (double)BB * (double)OHEI * (double)OWID;
            out[0] = (float)(1.0 - stot / N);
        }
    }
}

extern "C" void kernel_launch(void* const* d_in, const int* in_sizes, int n_in,
                              void* d_out, int out_size, void* d_ws, size_t ws_size,
                              hipStream_t stream)
{
    const float* X  = (const float*)d_in[0];
    const float* Y  = (const float*)d_in[1];
    const float* dr = (const float*)d_in[2];
    // d_in[3] is the box kernel w (all 1/49) — folded into constants.
    double*   acc     = (double*)d_ws;
    unsigned* counter = (unsigned*)((char*)d_ws + 8);
    float*    out     = (float*)d_out;

    hipMemsetAsync(d_ws, 0, 16, stream);
    ssim_main<<<dim3(NBLK), dim3(NTH), 0, stream>>>(X, Y, dr, acc, counter, out);
}

// Round 5
// 281.030 us; speedup vs baseline: 1.2306x; 1.2306x over previous
//
#include <hip/hip_runtime.h>

#define WW 320          // input width/height
#define OWID 314        // output cols
#define OHEI 314        // output rows
#define BB 64           // batch
#define RPB 28          // output rows per band
#define NBAND 12        // ceil(314/28); last band row-masked
#define NSTRIP 79       // ceil(314/4) output-col strips of 4
#define NROWS (RPB + 6) // 34 input rows streamed per thread
#define NTH 256
#define NBLK ((BB * NBAND * NSTRIP) / NTH)   // 64*12*79/256 = 237 exactly (one round)

// Load the 10 floats needed per plane: float4 + float4 + float2 (o2 clamps the
// tail strip in-bounds; duplicated cols are masked via cm).
__device__ __forceinline__ void load_row(
    const float* __restrict__ X0, const float* __restrict__ X1,
    const float* __restrict__ Y0, const float* __restrict__ Y1,
    int off, int o2, float4 r4[8], float2 r2[4])
{
    r4[0] = *(const float4*)(X0 + off);
    r4[1] = *(const float4*)(X0 + off + 4);
    r2[0] = *(const float2*)(X0 + off + o2);
    r4[2] = *(const float4*)(X1 + off);
    r4[3] = *(const float4*)(X1 + off + 4);
    r2[1] = *(const float2*)(X1 + off + o2);
    r4[4] = *(const float4*)(Y0 + off);
    r4[5] = *(const float4*)(Y0 + off + 4);
    r2[2] = *(const float2*)(Y0 + off + o2);
    r4[6] = *(const float4*)(Y1 + off);
    r4[7] = *(const float4*)(Y1 + off + 4);
    r2[3] = *(const float2*)(Y1 + off + o2);
}

// 4 horizontal 7-tap sums of the 5 channel-combined moments for one loaded row.
__device__ __forceinline__ void math_row(const float4 r4[8], const float2 r2[4], float h[20])
{
    float x0[10] = {r4[0].x, r4[0].y, r4[0].z, r4[0].w, r4[1].x, r4[1].y, r4[1].z, r4[1].w, r2[0].x, r2[0].y};
    float x1[10] = {r4[2].x, r4[2].y, r4[2].z, r4[2].w, r4[3].x, r4[3].y, r4[3].z, r4[3].w, r2[1].x, r2[1].y};
    float y0[10] = {r4[4].x, r4[4].y, r4[4].z, r4[4].w, r4[5].x, r4[5].y, r4[5].z, r4[5].w, r2[2].x, r2[2].y};
    float y1[10] = {r4[6].x, r4[6].y, r4[6].z, r4[6].w, r4[7].x, r4[7].y, r4[7].z, r4[7].w, r2[3].x, r2[3].y};

    float sx[10], sy[10], sxx[10], syy[10], sxy[10];
    #pragma unroll
    for (int j = 0; j < 10; ++j) {
        sx[j]  = x0[j] + x1[j];
        sy[j]  = y0[j] + y1[j];
        sxx[j] = x0[j] * x0[j] + x1[j] * x1[j];
        syy[j] = y0[j] * y0[j] + y1[j] * y1[j];
        sxy[j] = x0[j] * y0[j] + x1[j] * y1[j];
    }
    #pragma unroll
    for (int q = 0; q < 5; ++q) {
        const float* m = (q == 0) ? sx : (q == 1) ? sy : (q == 2) ? sxx : (q == 3) ? syy : sxy;
        float t0 = ((m[0] + m[1]) + (m[2] + m[3])) + ((m[4] + m[5]) + m[6]);
        float t1 = t0 - m[0] + m[7];
        float t2 = t1 - m[1] + m[8];
        float t3 = t2 - m[2] + m[9];
        h[q * 4 + 0] = t0; h[q * 4 + 1] = t1; h[q * 4 + 2] = t2; h[q * 4 + 3] = t3;
    }
}

// 1 block/CU by design (grid = 237 <= 256 CUs, single round). Ring history
// lives in LDS (thread-private slices, no syncs) to stay under the 256-VGPR
// arch ceiling (round 4: 370-reg demand -> 215 MB scratch spill traffic).
__global__ __launch_bounds__(NTH, 1) void ssim_main(
    const float* __restrict__ X, const float* __restrict__ Y,
    const float* __restrict__ dr, double* __restrict__ acc,
    unsigned* __restrict__ counter, float* __restrict__ out)
{
    // 7 slots x 256 threads x 20 floats = 143,360 B LDS (<= 160 KiB/CU).
    __shared__ float ring[7][NTH][20];

    const int wi   = blockIdx.x * NTH + threadIdx.x;   // grid sized exactly
    const int s    = wi % NSTRIP;
    const int g    = wi / NSTRIP;
    const int band = g % NBAND;
    const int b    = g / NBAND;
    const int r0   = band * RPB;
    const int cb   = s * 4;
    const int o2   = (cb <= 308) ? 8 : 4;   // clamp tail strip in-bounds

    const size_t plane = (size_t)WW * WW;
    const float* X0 = X + (size_t)b * 2 * plane;
    const float* X1 = X0 + plane;
    const float* Y0 = Y + (size_t)b * 2 * plane;
    const float* Y1 = Y0 + plane;

    const float d  = dr[b];
    const float C1 = (0.01f * d) * (0.01f * d);
    const float C2 = (0.03f * d) * (0.03f * d);

    float cm[4];
    #pragma unroll
    for (int j = 0; j < 4; ++j) cm[j] = (cb + j < OWID) ? 1.0f : 0.0f;

    float v[20];
    #pragma unroll
    for (int q = 0; q < 20; ++q) v[q] = 0.0f;

    // Depth-3 software pipeline: loads for row i+2 issued before math(i);
    // full unroll makes every buf/ring index static (no rotation movs).
    float4 b4[3][8];
    float2 b2[3][4];
    load_row(X0, X1, Y0, Y1, r0 * WW + cb, o2, b4[0], b2[0]);
    {
        const int rn = min(r0 + 1, WW - 1);
        load_row(X0, X1, Y0, Y1, rn * WW + cb, o2, b4[1], b2[1]);
    }

    float ssum = 0.0f;
    const float inv = 1.0f / 49.0f;
    const float cn  = 49.0f / 48.0f;
    float* const myring = &ring[0][threadIdx.x][0];   // slot stride = NTH*20 floats

    #pragma unroll
    for (int i = 0; i < NROWS; ++i) {
        if (i + 2 < NROWS) {                  // static guard: prefetch row r0+i+2
            const int rn = min(r0 + i + 2, WW - 1);   // clamp: tail band masked
            load_row(X0, X1, Y0, Y1, rn * WW + cb, o2, b4[(i + 2) % 3], b2[(i + 2) % 3]);
        }

        float h[20];
        math_row(b4[i % 3], b2[i % 3], h);    // waits ~2 iterations after issue

        float* rp = myring + (i % 7) * (NTH * 20);   // static slot offset

        if (i >= 7) {                         // static guard: expire row i-7
            float ro[20];
            #pragma unroll
            for (int q = 0; q < 5; ++q)
                *(float4*)&ro[4 * q] = *(const float4*)&rp[4 * q];
            #pragma unroll
            for (int q = 0; q < 20; ++q) v[q] += h[q] - ro[q];
        } else {
            #pragma unroll
            for (int q = 0; q < 20; ++q) v[q] += h[q];
        }

        if (i < NROWS - 7) {                  // static guard: h needed 7 rows later
            #pragma unroll
            for (int q = 0; q < 5; ++q)
                *(float4*)&rp[4 * q] = *(const float4*)&h[4 * q];
        }

        if (i >= 6) {                         // static guard
            const int t = r0 + i - 6;         // output row
            if (t < OHEI) {                   // runtime tail-band mask
                #pragma unroll
                for (int j = 0; j < 4; ++j) {
                    float ux  = v[j]      * inv, uy  = v[4 + j]  * inv;
                    float uxx = v[8 + j]  * inv, uyy = v[12 + j] * inv, uxy = v[16 + j] * inv;
                    float vx  = cn * (uxx - ux * ux);
                    float vy  = cn * (uyy - uy * uy);
                    float vxy = cn * (uxy - ux * uy);
                    float A1  = 2.0f * ux * uy + C1;
                    float A2  = 2.0f * vxy + C2;
                    float B1  = ux * ux + uy * uy + C1;
                    float B2  = vx + vy + C2;
                    ssum += cm[j] * (A1 * A2) / (B1 * B2);
                }
            }
        }
    }

    // ---- reduction: wave shuffle (double) -> LDS -> one atomic per block ----
    double local = (double)ssum;
    #pragma unroll
    for (int off = 32; off > 0; off >>= 1)
        local += __shfl_down(local, off, 64);
    __shared__ double wsum[NTH / 64];
    const int lane = threadIdx.x & 63, wid = threadIdx.x >> 6;
    if (lane == 0) wsum[wid] = local;
    __syncthreads();
    if (threadIdx.x == 0) {
        double tot = (wsum[0] + wsum[1]) + (wsum[2] + wsum[3]);
        atomicAdd(acc, tot);
        __threadfence();
        unsigned ticket = atomicAdd(counter, 1u);
        if (ticket == NBLK - 1) {
            double stot = atomicAdd(acc, 0.0);   // device-scope coherent read
            const double N = (double)BB * (double)OHEI * (double)OWID;
            out[0] = (float)(1.0 - stot / N);
        }
    }
}

extern "C" void kernel_launch(void* const* d_in, const int* in_sizes, int n_in,
                              void* d_out, int out_size, void* d_ws, size_t ws_size,
                              hipStream_t stream)
{
    const float* X  = (const float*)d_in[0];
    const float* Y  = (const float*)d_in[1];
    const float* dr = (const float*)d_in[2];
    // d_in[3] is the box kernel w (all 1/49) — folded into constants.
    double*   acc     = (double*)d_ws;
    unsigned* counter = (unsigned*)((char*)d_ws + 8);
    float*    out     = (float*)d_out;

    hipMemsetAsync(d_ws, 0, 16, stream);
    ssim_main<<<dim3(NBLK), dim3(NTH), 0, stream>>>(X, Y, dr, acc, counter, out);
}

// Round 6
// 209.471 us; speedup vs baseline: 1.6510x; 1.3416x over previous
//
#include <hip/hip_runtime.h>
#include <utility>

#define WW 320          // input width/height
#define OWID 314        // output cols
#define OHEI 314        // output rows
#define BB 64           // batch
#define RPB 28          // output rows per band
#define NBAND 12        // ceil(314/28); last band row-masked
#define NSTRIP 79       // ceil(314/4) output-col strips of 4
#define NROWS (RPB + 6) // 34 input rows streamed per thread
#define NTH 256
#define NBLK ((BB * NBAND * NSTRIP) / NTH)   // 64*12*79/256 = 237 exactly (one round)

// Load the 10 floats needed per plane: float4 + float4 + float2 (o2 clamps the
// tail strip in-bounds; duplicated cols are masked via cm).
__device__ __forceinline__ void load_row(
    const float* __restrict__ X0, const float* __restrict__ X1,
    const float* __restrict__ Y0, const float* __restrict__ Y1,
    int off, int o2, float4 r4[8], float2 r2[4])
{
    r4[0] = *(const float4*)(X0 + off);
    r4[1] = *(const float4*)(X0 + off + 4);
    r2[0] = *(const float2*)(X0 + off + o2);
    r4[2] = *(const float4*)(X1 + off);
    r4[3] = *(const float4*)(X1 + off + 4);
    r2[1] = *(const float2*)(X1 + off + o2);
    r4[4] = *(const float4*)(Y0 + off);
    r4[5] = *(const float4*)(Y0 + off + 4);
    r2[2] = *(const float2*)(Y0 + off + o2);
    r4[6] = *(const float4*)(Y1 + off);
    r4[7] = *(const float4*)(Y1 + off + 4);
    r2[3] = *(const float2*)(Y1 + off + o2);
}

// 4 horizontal 7-tap sums of the 5 channel-combined moments for one loaded row.
__device__ __forceinline__ void math_row(const float4 r4[8], const float2 r2[4], float h[20])
{
    float x0[10] = {r4[0].x, r4[0].y, r4[0].z, r4[0].w, r4[1].x, r4[1].y, r4[1].z, r4[1].w, r2[0].x, r2[0].y};
    float x1[10] = {r4[2].x, r4[2].y, r4[2].z, r4[2].w, r4[3].x, r4[3].y, r4[3].z, r4[3].w, r2[1].x, r2[1].y};
    float y0[10] = {r4[4].x, r4[4].y, r4[4].z, r4[4].w, r4[5].x, r4[5].y, r4[5].z, r4[5].w, r2[2].x, r2[2].y};
    float y1[10] = {r4[6].x, r4[6].y, r4[6].z, r4[6].w, r4[7].x, r4[7].y, r4[7].z, r4[7].w, r2[3].x, r2[3].y};

    float sx[10], sy[10], sxx[10], syy[10], sxy[10];
    #pragma unroll
    for (int j = 0; j < 10; ++j) {
        sx[j]  = x0[j] + x1[j];
        sy[j]  = y0[j] + y1[j];
        sxx[j] = x0[j] * x0[j] + x1[j] * x1[j];
        syy[j] = y0[j] * y0[j] + y1[j] * y1[j];
        sxy[j] = x0[j] * y0[j] + x1[j] * y1[j];
    }
    #pragma unroll
    for (int q = 0; q < 5; ++q) {
        const float* m = (q == 0) ? sx : (q == 1) ? sy : (q == 2) ? sxx : (q == 3) ? syy : sxy;
        float t0 = ((m[0] + m[1]) + (m[2] + m[3])) + ((m[4] + m[5]) + m[6]);
        float t1 = t0 - m[0] + m[7];
        float t2 = t1 - m[1] + m[8];
        float t3 = t2 - m[2] + m[9];
        h[q * 4 + 0] = t0; h[q * 4 + 1] = t1; h[q * 4 + 2] = t2; h[q * 4 + 3] = t3;
    }
}

// Compile-time unroll helper: calls f(integral_constant<int,0>), ..., f(<N-1>).
template <class F, int... Is>
__device__ __forceinline__ void for_seq(std::integer_sequence<int, Is...>, F&& f)
{
    (f(std::integral_constant<int, Is>{}), ...);
}

// One row step. CUR holds row r0+I on entry; after its math is consumed, the
// SAME buffer is refilled with row r0+I+2 (anti-dependency: bounds loads in
// flight to <= 2 rows by construction — no unbounded hoisting like R4/R5).
template <int I>
__device__ __forceinline__ void row_step(
    const float* __restrict__ X0, const float* __restrict__ X1,
    const float* __restrict__ Y0, const float* __restrict__ Y1,
    int r0, int cb, int o2,
    float4 CUR4[8], float2 CUR2[4],
    float ring[7][20], float v[20],
    const float cm[4], float c1, float c2, float& ssum)
{
    float h[20];
    math_row(CUR4, CUR2, h);                 // waits on loads issued at body I-2

    if constexpr (I + 2 < NROWS) {           // refill CUR with row r0+I+2
        const int rn = min(r0 + I + 2, WW - 1);   // clamp: tail band masked below
        load_row(X0, X1, Y0, Y1, rn * WW + cb, o2, CUR4, CUR2);
    }

    constexpr int slot = I % 7;              // static ring slot
    #pragma unroll
    for (int q = 0; q < 20; ++q) {
        v[q] += h[q] - ring[slot][q];        // add row I, expire row I-7
        ring[slot][q] = h[q];                // (ring zero-init: first 7 expires no-op)
    }

    if constexpr (I >= 6) {
        const int t = r0 + I - 6;            // output row
        if (t < OHEI) {                      // runtime tail-band mask
            const float inv = 1.0f / 49.0f;
            const float cn  = 49.0f / 48.0f;
            #pragma unroll
            for (int j = 0; j < 4; ++j) {
                float ux  = v[j]      * inv, uy  = v[4 + j]  * inv;
                float uxx = v[8 + j]  * inv, uyy = v[12 + j] * inv, uxy = v[16 + j] * inv;
                float vx  = cn * (uxx - ux * ux);
                float vy  = cn * (uyy - uy * uy);
                float vxy = cn * (uxy - ux * uy);
                float A1  = 2.0f * ux * uy + c1;
                float A2  = 2.0f * vxy + c2;
                float B1  = ux * ux + uy * uy + c1;
                float B2  = vx + vy + c2;
                ssum += cm[j] * (A1 * A2) / (B1 * B2);
            }
        }
    }
}

// 1 block/CU by design (grid = 237 <= 256 CUs, single round). Ring stays in
// registers (R3-proven, VGPR 184); R4/R5 variants that exceeded the 256-VGPR
// arch ceiling or used LDS ring both spilled to scratch (WRITE_SIZE in MB).
__global__ __launch_bounds__(NTH, 1) void ssim_main(
    const float* __restrict__ X, const float* __restrict__ Y,
    const float* __restrict__ dr, double* __restrict__ acc,
    unsigned* __restrict__ counter, float* __restrict__ out)
{
    const int wi   = blockIdx.x * NTH + threadIdx.x;   // grid sized exactly
    const int s    = wi % NSTRIP;
    const int g    = wi / NSTRIP;
    const int band = g % NBAND;
    const int b    = g / NBAND;
    const int r0   = band * RPB;
    const int cb   = s * 4;
    const int o2   = (cb <= 308) ? 8 : 4;   // clamp tail strip in-bounds

    const size_t plane = (size_t)WW * WW;
    const float* X0 = X + (size_t)b * 2 * plane;
    const float* X1 = X0 + plane;
    const float* Y0 = Y + (size_t)b * 2 * plane;
    const float* Y1 = Y0 + plane;

    const float d  = dr[b];
    const float c1 = (0.01f * d) * (0.01f * d);
    const float c2 = (0.03f * d) * (0.03f * d);

    float cm[4];
    #pragma unroll
    for (int j = 0; j < 4; ++j) cm[j] = (cb + j < OWID) ? 1.0f : 0.0f;

    float ring[7][20];
    #pragma unroll
    for (int k = 0; k < 7; ++k)
        #pragma unroll
        for (int q = 0; q < 20; ++q) ring[k][q] = 0.0f;

    float v[20];
    #pragma unroll
    for (int q = 0; q < 20; ++q) v[q] = 0.0f;

    // True ping-pong, no rotation: A = even rows, B = odd rows.
    float4 A4[8], B4[8];
    float2 A2[4], B2[4];
    load_row(X0, X1, Y0, Y1, r0 * WW + cb, o2, A4, A2);
    {
        const int rn = min(r0 + 1, WW - 1);
        load_row(X0, X1, Y0, Y1, rn * WW + cb, o2, B4, B2);
    }

    float ssum = 0.0f;

    for_seq(std::make_integer_sequence<int, NROWS>{}, [&](auto ic) {
        constexpr int I = decltype(ic)::value;
        if constexpr ((I & 1) == 0)
            row_step<I>(X0, X1, Y0, Y1, r0, cb, o2, A4, A2, ring, v, cm, c1, c2, ssum);
        else
            row_step<I>(X0, X1, Y0, Y1, r0, cb, o2, B4, B2, ring, v, cm, c1, c2, ssum);
    });

    // ---- reduction: wave shuffle (double) -> LDS -> one atomic per block ----
    double local = (double)ssum;
    #pragma unroll
    for (int off = 32; off > 0; off >>= 1)
        local += __shfl_down(local, off, 64);
    __shared__ double wsum[NTH / 64];
    const int lane = threadIdx.x & 63, wid = threadIdx.x >> 6;
    if (lane == 0) wsum[wid] = local;
    __syncthreads();
    if (threadIdx.x == 0) {
        double tot = (wsum[0] + wsum[1]) + (wsum[2] + wsum[3]);
        atomicAdd(acc, tot);
        __threadfence();
        unsigned ticket = atomicAdd(counter, 1u);
        if (ticket == NBLK - 1) {
            double stot = atomicAdd(acc, 0.0);   // device-scope coherent read
            const double N = (double)BB * (double)OHEI * (double)OWID;
            out[0] = (float)(1.0 - stot / N);
        }
    }
}

extern "C" void kernel_launch(void* const* d_in, const int* in_sizes, int n_in,
                              void* d_out, int out_size, void* d_ws, size_t ws_size,
                              hipStream_t stream)
{
    const float* X  = (const float*)d_in[0];
    const float* Y  = (const float*)d_in[1];
    const float* dr = (const float*)d_in[2];
    // d_in[3] is the box kernel w (all 1/49) — folded into constants.
    double*   acc     = (double*)d_ws;
    unsigned* counter = (unsigned*)((char*)d_ws + 8);
    float*    out     = (float*)d_out;

    hipMemsetAsync(d_ws, 0, 16, stream);
    ssim_main<<<dim3(NBLK), dim3(NTH), 0, stream>>>(X, Y, dr, acc, counter, out);
}

// Round 8
// 150.972 us; speedup vs baseline: 2.2907x; 1.3875x over previous
//
#include <hip/hip_runtime.h>

#define WW 320          // input width/height
#define OWID 314        // output cols
#define OHEI 314        // output rows
#define BB 64           // batch
#define RPB 28          // output rows per band
#define NBAND 12        // ceil(314/28); last band row-masked
#define NSTRIP 79       // ceil(314/4) output-col strips of 4
#define NROWS (RPB + 6) // 34 input rows streamed per thread
#define NTH 256
#define NBLK ((BB * NBAND * NSTRIP) / NTH)   // 64*12*79/256 = 237 exactly (one round)

// Load the 10 floats needed per plane: float4 + float4 + float2 (o2 clamps the
// tail strip in-bounds; duplicated cols are masked via cm).
__device__ __forceinline__ void load_row(
    const float* __restrict__ X0, const float* __restrict__ X1,
    const float* __restrict__ Y0, const float* __restrict__ Y1,
    int off, int o2, float4 r4[8], float2 r2[4])
{
    r4[0] = *(const float4*)(X0 + off);
    r4[1] = *(const float4*)(X0 + off + 4);
    r2[0] = *(const float2*)(X0 + off + o2);
    r4[2] = *(const float4*)(X1 + off);
    r4[3] = *(const float4*)(X1 + off + 4);
    r2[1] = *(const float2*)(X1 + off + o2);
    r4[4] = *(const float4*)(Y0 + off);
    r4[5] = *(const float4*)(Y0 + off + 4);
    r2[2] = *(const float2*)(Y0 + off + o2);
    r4[6] = *(const float4*)(Y1 + off);
    r4[7] = *(const float4*)(Y1 + off + 4);
    r2[3] = *(const float2*)(Y1 + off + o2);
}

// 4 horizontal 7-tap sums of FOUR channel-combined moments {sx, sy,
// s2 = sxx+syy, sxy} — SSIM only needs vx+vy, so sxx/syy merge (saves
// 28 ring regs + ~30 VALU/row vs the 5-moment form).
__device__ __forceinline__ void math_row(const float4 r4[8], const float2 r2[4], float h[16])
{
    float x0[10] = {r4[0].x, r4[0].y, r4[0].z, r4[0].w, r4[1].x, r4[1].y, r4[1].z, r4[1].w, r2[0].x, r2[0].y};
    float x1[10] = {r4[2].x, r4[2].y, r4[2].z, r4[2].w, r4[3].x, r4[3].y, r4[3].z, r4[3].w, r2[1].x, r2[1].y};
    float y0[10] = {r4[4].x, r4[4].y, r4[4].z, r4[4].w, r4[5].x, r4[5].y, r4[5].z, r4[5].w, r2[2].x, r2[2].y};
    float y1[10] = {r4[6].x, r4[6].y, r4[6].z, r4[6].w, r4[7].x, r4[7].y, r4[7].z, r4[7].w, r2[3].x, r2[3].y};

    float sx[10], sy[10], s2[10], sxy[10];
    #pragma unroll
    for (int j = 0; j < 10; ++j) {
        sx[j]  = x0[j] + x1[j];
        sy[j]  = y0[j] + y1[j];
        s2[j]  = x0[j] * x0[j] + x1[j] * x1[j] + y0[j] * y0[j] + y1[j] * y1[j];
        sxy[j] = x0[j] * y0[j] + x1[j] * y1[j];
    }
    #pragma unroll
    for (int q = 0; q < 4; ++q) {
        const float* m = (q == 0) ? sx : (q == 1) ? sy : (q == 2) ? s2 : sxy;
        float t0 = ((m[0] + m[1]) + (m[2] + m[3])) + ((m[4] + m[5]) + m[6]);
        float t1 = t0 - m[0] + m[7];
        float t2 = t1 - m[1] + m[8];
        float t3 = t2 - m[2] + m[9];
        h[q * 4 + 0] = t0; h[q * 4 + 1] = t1; h[q * 4 + 2] = t2; h[q * 4 + 3] = t3;
    }
}

// 1 block/CU by design (grid = 237 <= 256 CUs, single round). Ring in
// registers (7x16). Rolled outer loop (#pragma unroll 1) prevents the
// full-unroll live-range explosion that spilled R4/R5/R6; 14-body inner
// unroll makes ring slot (k%7) and buffer parity (k&1) static.
__global__ __launch_bounds__(NTH, 1) void ssim_main(
    const float* __restrict__ X, const float* __restrict__ Y,
    const float* __restrict__ dr, double* __restrict__ acc,
    unsigned* __restrict__ counter, float* __restrict__ out)
{
    const int wi   = blockIdx.x * NTH + threadIdx.x;   // grid sized exactly
    const int s    = wi % NSTRIP;
    const int g    = wi / NSTRIP;
    const int band = g % NBAND;
    const int b    = g / NBAND;
    const int r0   = band * RPB;
    const int cb   = s * 4;
    const int o2   = (cb <= 308) ? 8 : 4;   // clamp tail strip in-bounds

    const size_t plane = (size_t)WW * WW;
    const float* X0 = X + (size_t)b * 2 * plane;
    const float* X1 = X0 + plane;
    const float* Y0 = Y + (size_t)b * 2 * plane;
    const float* Y1 = Y0 + plane;

    const float d  = dr[b];
    const float C1 = (0.01f * d) * (0.01f * d);
    const float C2 = (0.03f * d) * (0.03f * d);

    float cm[4];
    #pragma unroll
    for (int j = 0; j < 4; ++j) cm[j] = (cb + j < OWID) ? 1.0f : 0.0f;

    float ring[7][16];
    #pragma unroll
    for (int k = 0; k < 7; ++k)
        #pragma unroll
        for (int q = 0; q < 16; ++q) ring[k][q] = 0.0f;

    float v[16];
    #pragma unroll
    for (int q = 0; q < 16; ++q) v[q] = 0.0f;

    // Ping-pong row buffers: A = even rows, B = odd rows. Each body consumes
    // its buffer then refills the SAME buffer with row i+2 — the
    // anti-dependency bounds loads in flight to <= 2 rows by construction.
    float4 A4[8], B4[8];
    float2 A2[4], B2[4];
    load_row(X0, X1, Y0, Y1, r0 * WW + cb, o2, A4, A2);
    load_row(X0, X1, Y0, Y1, (r0 + 1) * WW + cb, o2, B4, B2);

    float ssum = 0.0f;
    const float inv = 1.0f / 49.0f;
    const float cn  = 49.0f / 48.0f;

    // i7 in {0,14,28}: 14 | both 7 (ring) and 2 (parity) alignment, so all
    // inner indices are static. Bodies i >= NROWS are cheap dead steps.
    #pragma unroll 1
    for (int i7 = 0; i7 < 42; i7 += 14) {
        #pragma unroll
        for (int k = 0; k < 14; ++k) {
            const int i = i7 + k;             // row index r0+i

            float h[16];
            if (k & 1) math_row(B4, B2, h);   // waits on loads issued 2 bodies ago
            else       math_row(A4, A2, h);

            if (i + 2 < NROWS) {              // refill same buffer with row i+2
                const int rn = min(r0 + i + 2, WW - 1);   // clamp: tail masked
                if (k & 1) load_row(X0, X1, Y0, Y1, rn * WW + cb, o2, B4, B2);
                else       load_row(X0, X1, Y0, Y1, rn * WW + cb, o2, A4, A2);
            }

            if (i < NROWS) {                  // live body (uniform branch)
                const int slot = k % 7;       // == i % 7 (i7 multiple of 7)
                #pragma unroll
                for (int q = 0; q < 16; ++q) {
                    v[q] += h[q] - ring[slot][q];   // add row i, expire row i-7
                    ring[slot][q] = h[q];           // (zero-init: first 7 no-op)
                }

                if (i >= 6) {
                    const int t = r0 + i - 6;       // output row
                    if (t < OHEI) {                 // runtime tail-band mask
                        #pragma unroll
                        for (int j = 0; j < 4; ++j) {
                            float ux  = v[j]      * inv;
                            float uy  = v[4 + j]  * inv;
                            float u2  = v[8 + j]  * inv;   // uxx + uyy
                            float uxy = v[12 + j] * inv;
                            float vxy = cn * (uxy - ux * uy);
                            float v2  = cn * (u2 - ux * ux - uy * uy);  // vx+vy
                            float A1  = 2.0f * ux * uy + C1;
                            float A2  = 2.0f * vxy + C2;
                            float B1  = ux * ux + uy * uy + C1;
                            float B2  = v2 + C2;
                            ssum += cm[j] * (A1 * A2) / (B1 * B2);
                        }
                    }
                }
            }
        }
    }

    // ---- reduction: wave shuffle (double) -> LDS -> one atomic per block ----
    double local = (double)ssum;
    #pragma unroll
    for (int off = 32; off > 0; off >>= 1)
        local += __shfl_down(local, off, 64);
    __shared__ double wsum[NTH / 64];
    const int lane = threadIdx.x & 63, wid = threadIdx.x >> 6;
    if (lane == 0) wsum[wid] = local;
    __syncthreads();
    if (threadIdx.x == 0) {
        double tot = (wsum[0] + wsum[1]) + (wsum[2] + wsum[3]);
        atomicAdd(acc, tot);
        __threadfence();
        unsigned ticket = atomicAdd(counter, 1u);
        if (ticket == NBLK - 1) {
            double stot = atomicAdd(acc, 0.0);   // device-scope coherent read
            const double N = (double)BB * (double)OHEI * (double)OWID;
            out[0] = (float)(1.0 - stot / N);
        }
    }
}

extern "C" void kernel_launch(void* const* d_in, const int* in_sizes, int n_in,
                              void* d_out, int out_size, void* d_ws, size_t ws_size,
                              hipStream_t stream)
{
    const float* X  = (const float*)d_in[0];
    const float* Y  = (const float*)d_in[1];
    const float* dr = (const float*)d_in[2];
    // d_in[3] is the box kernel w (all 1/49) — folded into constants.
    double*   acc     = (double*)d_ws;
    unsigned* counter = (unsigned*)((char*)d_ws + 8);
    float*    out     = (float*)d_out;

    hipMemsetAsync(d_ws, 0, 16, stream);
    ssim_main<<<dim3(NBLK), dim3(NTH), 0, stream>>>(X, Y, dr, acc, counter, out);
}